// Round 7
// baseline (105.413 us; speedup 1.0000x reference)
//
#include <hip/hip_runtime.h>
#include <hip/hip_bf16.h>
#include <math.h>

// B=8192, D=1024, H=128, C=16
// out tuple: masked[B*D], mask_norm(0.0), embed_norm(||x||F), x[B*D] -> f32
#define B_ 8192
#define D_ 1024
#define H_ 128
#define C_ 16
#define BD (B_*D_)
#define STM 16              // rows per subtile
#define MAXSUB 516          // worst-case subtiles per XCD

using bf16x8 = __attribute__((ext_vector_type(8))) __bf16;
using f32x4  = __attribute__((ext_vector_type(4))) float;
typedef unsigned short ushort_t;

// ws layout (bytes):
//   int idx 16      : nsub[8]
//   int idx 32      : subtbl[8][516][3] (cond,row0,end)
//   int idx 16384   : sidx[8192]   (byte 65536)   sorted-pos -> orig row
//   int idx 24576   : inv[8192]    (byte 98304)   orig row -> sorted-pos
//   131072          : ep[16] f32
//   262144          : w1s bf16 (4 MiB)  [cond][ks32][jf8][l15][kg][8]
//   4456448         : w2s bf16 (4 MiB)  [cond][ks4][jf64][l15][kg][8]
//   8650752         : xbfs bf16 (16 MiB) [sorted_row][k]

__device__ inline bf16x8 cvt8(float4 a, float4 b) {
    bf16x8 r;
    r[0] = (__bf16)a.x; r[1] = (__bf16)a.y; r[2] = (__bf16)a.z; r[3] = (__bf16)a.w;
    r[4] = (__bf16)b.x; r[5] = (__bf16)b.y; r[6] = (__bf16)b.z; r[7] = (__bf16)b.w;
    return r;
}

// ---- histogram + per-XCD subtile table + scatter (fwd & inverse); zeroes ep ----
__global__ __launch_bounds__(1024) void k_sort(const int* __restrict__ c,
                                               int* __restrict__ w,
                                               float* __restrict__ ep) {
    __shared__ int hist[C_], base[C_];
    int tid = threadIdx.x;
    if (tid < C_) { hist[tid] = 0; ep[tid] = 0.0f; }
    __syncthreads();
    int myc[8];
#pragma unroll
    for (int i = 0; i < 8; ++i) {
        myc[i] = c[tid * 8 + i];
        atomicAdd(&hist[myc[i]], 1);
    }
    __syncthreads();
    if (tid == 0) {
        int off = 0; int ns[8] = {0,0,0,0,0,0,0,0};
        for (int cc = 0; cc < C_; ++cc) {
            int cnt = hist[cc]; base[cc] = off;
            int xcd = cc >> 1;                 // 2 conds/XCD -> 1MB bf16 weights in its L2
            for (int t = 0; t < cnt; t += STM) {
                int s = ns[xcd]++;
                int* e = &w[32 + (xcd * MAXSUB + s) * 3];
                e[0] = cc; e[1] = off + t; e[2] = off + cnt;
            }
            off += cnt;
        }
        for (int xx = 0; xx < 8; ++xx) w[16 + xx] = ns[xx];
    }
    __syncthreads();
#pragma unroll
    for (int i = 0; i < 8; ++i) {
        int b = tid * 8 + i;
        int pos = atomicAdd(&base[myc[i]], 1);
        w[16384 + pos] = b;        // sidx
        w[24576 + b]   = pos;      // inverse
    }
}

// ---- prep: x -> sorted bf16 + x copy + ||x||^2 ; W1,W2 -> bf16 fragment order ----
__global__ __launch_bounds__(256) void k_prep(const float* __restrict__ x,
                                              const float* __restrict__ W1f,
                                              const float* __restrict__ W2f,
                                              float* __restrict__ out,
                                              __bf16* __restrict__ xbfs,
                                              __bf16* __restrict__ w1s,
                                              __bf16* __restrict__ w2s,
                                              const int* __restrict__ inv,
                                              float* __restrict__ ep) {
    int bid = blockIdx.x, tid = threadIdx.x;
    if (bid < 1024) {                       // x: 8 rows per block
        float xsq = 0.0f;
#pragma unroll
        for (int u = 0; u < 4; ++u) {
            int r = bid * 8 + u * 2 + (tid >> 7);
            int col = (tid & 127) * 8;
            const float* xs = x + (size_t)r * D_ + col;
            float4 pv = *(const float4*)xs, qv = *(const float4*)(xs + 4);
            float2* xo = (float2*)(out + (size_t)BD + 2 + (size_t)r * D_ + col);
            xo[0] = make_float2(pv.x, pv.y); xo[1] = make_float2(pv.z, pv.w);
            xo[2] = make_float2(qv.x, qv.y); xo[3] = make_float2(qv.z, qv.w);
            int pr = inv[r];
            *(bf16x8*)(xbfs + (size_t)pr * D_ + col) = cvt8(pv, qv);
            xsq += pv.x*pv.x + pv.y*pv.y + pv.z*pv.z + pv.w*pv.w
                 + qv.x*qv.x + qv.y*qv.y + qv.z*qv.z + qv.w*qv.w;
        }
        float s = xsq;
        s += __shfl_xor(s, 1);  s += __shfl_xor(s, 2);  s += __shfl_xor(s, 4);
        s += __shfl_xor(s, 8);  s += __shfl_xor(s, 16); s += __shfl_xor(s, 32);
        __shared__ float red[4];
        int lane = tid & 63, wv = tid >> 6;
        if (lane == 0) red[wv] = s;
        __syncthreads();
        if (tid == 0) atomicAdd(&ep[bid & 15], red[0] + red[1] + red[2] + red[3]);
    } else if (bid < 1152) {                // W1 -> w1s
        int wb = bid - 1024;
#pragma unroll
        for (int u = 0; u < 8; ++u) {
            int g = wb * 2048 + u * 256 + tid;
            int cond = g >> 14, rem = g & 16383;
            int ks = rem >> 9, rem2 = rem & 511;
            int jf = rem2 >> 6, lam = rem2 & 63;
            int l15 = lam >> 2, kg = lam & 3;
            const float* src = W1f + ((size_t)cond * 128 + jf * 16 + l15) * 1024 + ks * 32 + kg * 8;
            *(bf16x8*)(w1s + (size_t)g * 8) = cvt8(*(const float4*)src, *(const float4*)(src + 4));
        }
    } else {                                // W2 -> w2s
        int wb = bid - 1152;
#pragma unroll
        for (int u = 0; u < 8; ++u) {
            int g = wb * 2048 + u * 256 + tid;
            int cond = g >> 14, rem = g & 16383;
            int ks = rem >> 12, rem2 = rem & 4095;
            int jf = rem2 >> 6, lam = rem2 & 63;
            int l15 = lam >> 2, kg = lam & 3;
            const float* src = W2f + ((size_t)cond * 1024 + jf * 16 + l15) * 128 + ks * 32 + kg * 8;
            *(bf16x8*)(w2s + (size_t)g * 8) = cvt8(*(const float4*)src, *(const float4*)(src + 4));
        }
    }
}

// ---- fused MLP + normalize: 512 thr (8 waves), one 16-row subtile per block ----
__global__ __launch_bounds__(512, 4) void k_f(const __bf16* __restrict__ xbfs,
                                              const __bf16* __restrict__ w1s,
                                              const __bf16* __restrict__ w2s,
                                              const float* __restrict__ b1f,
                                              const float* __restrict__ b2f,
                                              const int* __restrict__ wsi,
                                              float* __restrict__ out) {
    int xcd = blockIdx.x & 7, slot0 = blockIdx.x >> 3;
    int nsub = wsi[16 + xcd];
    const int* sidx = wsi + 16384;

    __shared__ ushort_t Hs[16 * 128];   // 4 KB h tile (slot-XOR swizzled)
    __shared__ float sqs[16 * 8];       // per-row per-wave sumsq

    int tid = threadIdx.x, wv = tid >> 6, lane = tid & 63, l15 = lane & 15, kg = lane >> 4;
    int lofs = (l15 * 4 + kg) * 16;     // fragment-order lane byte offset

    for (int si = slot0; si < nsub; si += 64) {
        const int* e = wsi + 32 + (xcd * MAXSUB + si) * 3;
        int cond = e[0], row0 = e[1], end = e[2];
        int p = row0 + l15, pcl = p < end ? p : end - 1;

        // ===== L1: wave wv computes h cols [wv*16,+16); barrier-free K-loop =====
        const char* aAdr = (const char*)xbfs + (size_t)pcl * 2048 + kg * 16;
        const char* bAdr = (const char*)w1s + (size_t)cond * 262144 + wv * 1024 + lofs;
        f32x4 acc = {};
#pragma unroll 8
        for (int ks = 0; ks < 32; ++ks) {
            bf16x8 a = *(const bf16x8*)(aAdr + ks * 64);
            bf16x8 b = *(const bf16x8*)(bAdr + (size_t)ks * 8192);
            acc = __builtin_amdgcn_mfma_f32_16x16x32_bf16(a, b, acc, 0, 0, 0);
        }
        {   // h + b1 -> Hs (swizzled bf16)
            int j0 = wv * 16 + l15;
            float bias = b1f[cond * 128 + j0];
            int sl0 = j0 >> 3, jb = j0 & 7;
#pragma unroll
            for (int v = 0; v < 4; ++v) {
                int r = kg * 4 + v;
                __bf16 hv = (__bf16)(acc[v] + bias);
                Hs[r * 128 + ((sl0 ^ (r & 7)) * 8) + jb] = __builtin_bit_cast(ushort_t, hv);
            }
        }
        __syncthreads();
        bf16x8 pa0 = *(const bf16x8*)(Hs + l15 * 128 + (((0  + kg) ^ (l15 & 7)) * 8));
        bf16x8 pa1 = *(const bf16x8*)(Hs + l15 * 128 + (((4  + kg) ^ (l15 & 7)) * 8));
        bf16x8 pa2 = *(const bf16x8*)(Hs + l15 * 128 + (((8  + kg) ^ (l15 & 7)) * 8));
        bf16x8 pa3 = *(const bf16x8*)(Hs + l15 * 128 + (((12 + kg) ^ (l15 & 7)) * 8));

        int bbs[4];
#pragma unroll
        for (int v = 0; v < 4; ++v) {
            int pr = row0 + kg * 4 + v;
            bbs[v] = (pr < end) ? sidx[pr] : -1;
        }

        // ===== L2: wave wv owns out cols [wv*128,+128); values held in regs =====
        const char* w2b = (const char*)w2s + (size_t)cond * 262144 + (size_t)wv * 8192 + lofs;
        float vals[8][4];
        float sq[4] = {0.f, 0.f, 0.f, 0.f};
#pragma unroll
        for (int f = 0; f < 8; ++f) {
            bf16x8 q0 = *(const bf16x8*)(w2b + f * 1024);
            bf16x8 q1 = *(const bf16x8*)(w2b + f * 1024 + 65536);
            bf16x8 q2 = *(const bf16x8*)(w2b + f * 1024 + 131072);
            bf16x8 q3 = *(const bf16x8*)(w2b + f * 1024 + 196608);
            f32x4 a2 = {};
            a2 = __builtin_amdgcn_mfma_f32_16x16x32_bf16(pa0, q0, a2, 0, 0, 0);
            a2 = __builtin_amdgcn_mfma_f32_16x16x32_bf16(pa1, q1, a2, 0, 0, 0);
            a2 = __builtin_amdgcn_mfma_f32_16x16x32_bf16(pa2, q2, a2, 0, 0, 0);
            a2 = __builtin_amdgcn_mfma_f32_16x16x32_bf16(pa3, q3, a2, 0, 0, 0);
            int jg = (wv * 8 + f) * 16 + l15;
            float bias = b2f[cond * 1024 + jg];
#pragma unroll
            for (int v = 0; v < 4; ++v) {
                float t = a2[v] + bias;
                vals[f][v] = t;
                sq[v] += t * t;
            }
        }
        // per-row sums: shfl over l15 -> LDS across waves
#pragma unroll
        for (int v = 0; v < 4; ++v) {
            float s = sq[v];
            s += __shfl_xor(s, 1); s += __shfl_xor(s, 2);
            s += __shfl_xor(s, 4); s += __shfl_xor(s, 8);
            if (l15 == 0) sqs[(kg * 4 + v) * 8 + wv] = s;
        }
        __syncthreads();
        float invn[4];
#pragma unroll
        for (int v = 0; v < 4; ++v) {
            int r = kg * 4 + v;
            float s = sqs[r*8+0] + sqs[r*8+1] + sqs[r*8+2] + sqs[r*8+3]
                    + sqs[r*8+4] + sqs[r*8+5] + sqs[r*8+6] + sqs[r*8+7];
            invn[v] = 1.0f / (sqrtf(s) + 1e-10f);
        }
        // normalized store
#pragma unroll
        for (int f = 0; f < 8; ++f) {
            int jg = (wv * 8 + f) * 16 + l15;
#pragma unroll
            for (int v = 0; v < 4; ++v)
                if (bbs[v] >= 0) out[(size_t)bbs[v] * D_ + jg] = vals[f][v] * invn[v];
        }
        __syncthreads();   // protect Hs/sqs for next subtile
    }
}

__global__ void k_fin(const float* __restrict__ ep, float* __restrict__ out) {
    float s = 0.0f;
#pragma unroll
    for (int i = 0; i < 16; ++i) s += ep[i];
    out[BD] = 0.0f;
    out[BD + 1] = sqrtf(s);
}

extern "C" void kernel_launch(void* const* d_in, const int* in_sizes, int n_in,
                              void* d_out, int out_size, void* d_ws, size_t ws_size,
                              hipStream_t stream) {
    const float* x  = (const float*)d_in[0];
    const int*   c  = (const int*)d_in[1];
    const float* W1 = (const float*)d_in[2];
    const float* b1 = (const float*)d_in[3];
    const float* W2 = (const float*)d_in[4];
    const float* b2 = (const float*)d_in[5];
    float* out = (float*)d_out;
    char* ws = (char*)d_ws;
    int* wsi = (int*)ws;
    float* ep    = (float*)(ws + 131072);
    __bf16* w1s  = (__bf16*)(ws + 262144);
    __bf16* w2s  = (__bf16*)(ws + 4456448);
    __bf16* xbfs = (__bf16*)(ws + 8650752);

    k_sort<<<1, 1024, 0, stream>>>(c, wsi, ep);
    k_prep<<<1280, 256, 0, stream>>>(x, W1, W2, out, xbfs, w1s, w2s, wsi + 24576, ep);
    k_f<<<512, 512, 0, stream>>>(xbfs, w1s, w2s, b1, b2, wsi, out);
    k_fin<<<1, 1, 0, stream>>>(ep, out);
}

// Round 8
// 91.134 us; speedup vs baseline: 1.1567x; 1.1567x over previous
//
#include <hip/hip_runtime.h>
#include <hip/hip_bf16.h>
#include <math.h>

// B=8192, D=1024, H=128, C=16
// out tuple: masked[B*D], mask_norm(0.0), embed_norm(||x||F), x[B*D] -> f32
#define B_ 8192
#define D_ 1024
#define H_ 128
#define C_ 16
#define BD (B_*D_)
#define SUBR 32             // rows per subtile (padded per cond)
#define SLOTS 34            // slots per XCD; grid = 8*34 = 272
#define MAXSUB 300

using bf16x8 = __attribute__((ext_vector_type(8))) __bf16;
using f32x4  = __attribute__((ext_vector_type(4))) float;
typedef unsigned short ushort_t;

// ws layout (bytes):
//   int 16      : nsub[8]
//   int 32      : subtbl[8][300][3] (cond, prow0, end)   (ints 32..7232)
//   int 8192    : sidx[8704]  padded sorted-pos -> orig row   (byte 32768)
//   int 20480   : inv[8192]   orig row -> padded sorted-pos   (byte 81920)
//   131072      : ep[16] f32
//   262144      : w1s bf16 (4 MiB)  [cond][jf8][ks32][lane64][8]
//   4456448     : w2s bf16 (4 MiB)  [cond][jf64][ks4][lane64][8]
//   8650752     : xbf bf16 (~17 MiB) [subtile][rg2][ks32][lane64][8]

__device__ inline bf16x8 cvt8(float4 a, float4 b) {
    bf16x8 r;
    r[0] = (__bf16)a.x; r[1] = (__bf16)a.y; r[2] = (__bf16)a.z; r[3] = (__bf16)a.w;
    r[4] = (__bf16)b.x; r[5] = (__bf16)b.y; r[6] = (__bf16)b.z; r[7] = (__bf16)b.w;
    return r;
}
__device__ inline unsigned pack2(float a, float b) {
    unsigned ua = __builtin_bit_cast(unsigned short, (__bf16)a);
    unsigned ub = __builtin_bit_cast(unsigned short, (__bf16)b);
    return ua | (ub << 16);
}
__device__ inline float unpk(unsigned p, int hi) {
    return (float)__builtin_bit_cast(__bf16, (unsigned short)(hi ? (p >> 16) : (p & 0xffff)));
}

// ---- histogram + padded per-XCD subtile table + scatter (fwd & inverse); zeroes ep ----
__global__ __launch_bounds__(1024) void k_sort(const int* __restrict__ c,
                                               int* __restrict__ w,
                                               float* __restrict__ ep) {
    __shared__ int hist[C_], base[C_];
    int tid = threadIdx.x;
    if (tid < C_) { hist[tid] = 0; ep[tid] = 0.0f; }
    __syncthreads();
    int myc[8];
#pragma unroll
    for (int i = 0; i < 8; ++i) {
        myc[i] = c[tid * 8 + i];
        atomicAdd(&hist[myc[i]], 1);
    }
    __syncthreads();
    if (tid == 0) {
        int off = 0; int ns[8] = {0,0,0,0,0,0,0,0};
        for (int cc = 0; cc < C_; ++cc) {
            int cnt = hist[cc]; base[cc] = off;
            int nt = (cnt + SUBR - 1) >> 5;
            int xcd = cc >> 1;
            for (int t = 0; t < nt; ++t) {
                int s = ns[xcd]++;
                int* e = &w[32 + (xcd * MAXSUB + s) * 3];
                e[0] = cc; e[1] = off + t * SUBR; e[2] = off + cnt;
            }
            off += nt * SUBR;              // padded to 32-row alignment
        }
        for (int xx = 0; xx < 8; ++xx) w[16 + xx] = ns[xx];
    }
    __syncthreads();
#pragma unroll
    for (int i = 0; i < 8; ++i) {
        int b = tid * 8 + i;
        int pos = atomicAdd(&base[myc[i]], 1);
        w[8192 + pos]  = b;     // sidx (padded positions)
        w[20480 + b]   = pos;   // inverse
    }
}

// ---- prep: x -> fragment-ordered bf16 + x copy + ||x||^2 ; W1,W2 -> bf16 streams ----
__global__ __launch_bounds__(256) void k_prep(const float* __restrict__ x,
                                              const float* __restrict__ W1f,
                                              const float* __restrict__ W2f,
                                              float* __restrict__ out,
                                              __bf16* __restrict__ xbf,
                                              __bf16* __restrict__ w1s,
                                              __bf16* __restrict__ w2s,
                                              const int* __restrict__ inv,
                                              float* __restrict__ ep) {
    int bid = blockIdx.x, tid = threadIdx.x;
    if (bid < 1024) {                       // x: 8 rows per block
        float xsq = 0.0f;
#pragma unroll
        for (int u = 0; u < 4; ++u) {
            int r = bid * 8 + u * 2 + (tid >> 7);
            int m = tid & 127;              // 16B chunk index within row
            const float* xs = x + (size_t)r * D_ + m * 8;
            float4 pv = *(const float4*)xs, qv = *(const float4*)(xs + 4);
            float2* xo = (float2*)(out + (size_t)BD + 2 + (size_t)r * D_ + m * 8);
            xo[0] = make_float2(pv.x, pv.y); xo[1] = make_float2(pv.z, pv.w);
            xo[2] = make_float2(qv.x, qv.y); xo[3] = make_float2(qv.z, qv.w);
            int pr = inv[r];
            int blk = pr >> 5, rg = (pr >> 4) & 1, r15 = pr & 15;
            int ks = m >> 2, kg = m & 3;
            size_t de = (size_t)blk * 32768 + (rg * 32 + ks) * 512 + (kg * 16 + r15) * 8;
            *(bf16x8*)(xbf + de) = cvt8(pv, qv);
            xsq += pv.x*pv.x + pv.y*pv.y + pv.z*pv.z + pv.w*pv.w
                 + qv.x*qv.x + qv.y*qv.y + qv.z*qv.z + qv.w*qv.w;
        }
        float s = xsq;
        s += __shfl_xor(s, 1);  s += __shfl_xor(s, 2);  s += __shfl_xor(s, 4);
        s += __shfl_xor(s, 8);  s += __shfl_xor(s, 16); s += __shfl_xor(s, 32);
        __shared__ float red[4];
        int lane = tid & 63, wv = tid >> 6;
        if (lane == 0) red[wv] = s;
        __syncthreads();
        if (tid == 0) atomicAdd(&ep[bid & 15], red[0] + red[1] + red[2] + red[3]);
    } else if (bid < 1152) {                // W1 -> w1s [cond][jf8][ks32][lane]
        int wb = bid - 1024;
#pragma unroll
        for (int u = 0; u < 8; ++u) {
            int g = wb * 2048 + u * 256 + tid;
            int cond = g >> 14, jf = (g >> 11) & 7, ks = (g >> 6) & 31, lam = g & 63;
            int l15 = lam & 15, kg = lam >> 4;
            const float* src = W1f + ((size_t)cond * 128 + jf * 16 + l15) * 1024 + ks * 32 + kg * 8;
            *(bf16x8*)(w1s + (size_t)g * 8) = cvt8(*(const float4*)src, *(const float4*)(src + 4));
        }
    } else {                                // W2 -> w2s [cond][jf64][ks4][lane]
        int wb = bid - 1152;
#pragma unroll
        for (int u = 0; u < 8; ++u) {
            int g = wb * 2048 + u * 256 + tid;
            int cond = g >> 14, jf = (g >> 8) & 63, ks = (g >> 6) & 3, lam = g & 63;
            int l15 = lam & 15, kg = lam >> 4;
            const float* src = W2f + ((size_t)cond * 1024 + jf * 16 + l15) * 128 + ks * 32 + kg * 8;
            *(bf16x8*)(w2s + (size_t)g * 8) = cvt8(*(const float4*)src, *(const float4*)(src + 4));
        }
    }
}

// ---- fused MLP + normalize: 512 thr, 32-row subtile, x via LDS, weights direct ----
__global__ __launch_bounds__(512, 4) void k_f(const __bf16* __restrict__ xbf,
                                              const __bf16* __restrict__ w1s,
                                              const __bf16* __restrict__ w2s,
                                              const float* __restrict__ b1f,
                                              const float* __restrict__ b2f,
                                              const int* __restrict__ wsi,
                                              float* __restrict__ out) {
    int xcd = blockIdx.x & 7, slot0 = blockIdx.x >> 3;
    int nsub = wsi[16 + xcd];
    const int* sidx = wsi + 8192;

    __shared__ ulong2 lds_raw[4096];        // 64 KB: x frags; aliased: Hs (8KB) + sqs @32KB
    char* lds = (char*)lds_raw;
    ushort_t* Hs = (ushort_t*)lds;
    float* sqs = (float*)(lds + 32768);

    int tid = threadIdx.x, wv = tid >> 6, lane = tid & 63, l15 = lane & 15, kg = lane >> 4;

    for (int si = slot0; si < nsub; si += SLOTS) {
        const int* e = wsi + 32 + (xcd * MAXSUB + si) * 3;
        int cond = e[0], prow0 = e[1], end = e[2];
        int blk = prow0 >> 5;

        // ---- stage x subtile: 64 KB contiguous copy ----
        {
            const char* src = (const char*)xbf + (size_t)blk * 65536 + tid * 16;
#pragma unroll
            for (int i = 0; i < 8; ++i) {
                bf16x8 v = *(const bf16x8*)(src + i * 8192);
                *(bf16x8*)(lds + i * 8192 + tid * 16) = v;
            }
        }
        __syncthreads();

        // ---- L1: wave wv computes h cols [wv*16,+16) for 32 rows ----
        const char* bA = (const char*)w1s + (size_t)cond * 262144 + wv * 32768 + lane * 16;
        f32x4 a00 = {}, a01 = {}, a10 = {}, a11 = {};
#pragma unroll 8
        for (int ks = 0; ks < 32; ++ks) {
            bf16x8 b  = *(const bf16x8*)(bA + ks * 1024);
            bf16x8 x0 = *(const bf16x8*)(lds + ks * 1024 + lane * 16);
            bf16x8 x1 = *(const bf16x8*)(lds + 32768 + ks * 1024 + lane * 16);
            if (ks & 1) {
                a01 = __builtin_amdgcn_mfma_f32_16x16x32_bf16(x0, b, a01, 0, 0, 0);
                a11 = __builtin_amdgcn_mfma_f32_16x16x32_bf16(x1, b, a11, 0, 0, 0);
            } else {
                a00 = __builtin_amdgcn_mfma_f32_16x16x32_bf16(x0, b, a00, 0, 0, 0);
                a10 = __builtin_amdgcn_mfma_f32_16x16x32_bf16(x1, b, a10, 0, 0, 0);
            }
        }
        __syncthreads();   // x reads done before Hs overwrites region

        // ---- h + b1 -> Hs (swizzled bf16) ----
        {
            int j0 = wv * 16 + l15;
            float bias = b1f[cond * 128 + j0];
            int sl0 = j0 >> 3, jb = j0 & 7;
#pragma unroll
            for (int v = 0; v < 4; ++v) {
                int r0 = kg * 4 + v;
                __bf16 h0 = (__bf16)(a00[v] + a01[v] + bias);
                __bf16 h1 = (__bf16)(a10[v] + a11[v] + bias);
                Hs[r0 * 128 + ((sl0 ^ (r0 & 7)) * 8) + jb] = __builtin_bit_cast(ushort_t, h0);
                int r1 = 16 + r0;
                Hs[r1 * 128 + ((sl0 ^ (r1 & 7)) * 8) + jb] = __builtin_bit_cast(ushort_t, h1);
            }
        }
        __syncthreads();

        // ---- pa fragments + row indices ----
        bf16x8 pa[2][4];
#pragma unroll
        for (int rg = 0; rg < 2; ++rg)
#pragma unroll
            for (int i = 0; i < 4; ++i)
                pa[rg][i] = *(const bf16x8*)(Hs + (rg * 16 + l15) * 128 + (((i * 4 + kg) ^ (l15 & 7)) * 8));
        int bbs[2][4];
#pragma unroll
        for (int rg = 0; rg < 2; ++rg)
#pragma unroll
            for (int v = 0; v < 4; ++v) {
                int pr = prow0 + rg * 16 + kg * 4 + v;
                bbs[rg][v] = (pr < end) ? sidx[pr] : -1;
            }

        // ---- L2: wave wv owns out cols [wv*128,+128); vals packed bf16 ----
        const char* w2b = (const char*)w2s + (size_t)cond * 262144 + wv * 32768 + lane * 16;
        unsigned vals[8][4];
        float sq[2][4] = {{0,0,0,0},{0,0,0,0}};
#pragma unroll
        for (int f = 0; f < 8; ++f) {
            bf16x8 q0 = *(const bf16x8*)(w2b + f * 4096);
            bf16x8 q1 = *(const bf16x8*)(w2b + f * 4096 + 1024);
            bf16x8 q2 = *(const bf16x8*)(w2b + f * 4096 + 2048);
            bf16x8 q3 = *(const bf16x8*)(w2b + f * 4096 + 3072);
            f32x4 c0 = {}, c1 = {};
            c0 = __builtin_amdgcn_mfma_f32_16x16x32_bf16(pa[0][0], q0, c0, 0, 0, 0);
            c1 = __builtin_amdgcn_mfma_f32_16x16x32_bf16(pa[1][0], q0, c1, 0, 0, 0);
            c0 = __builtin_amdgcn_mfma_f32_16x16x32_bf16(pa[0][1], q1, c0, 0, 0, 0);
            c1 = __builtin_amdgcn_mfma_f32_16x16x32_bf16(pa[1][1], q1, c1, 0, 0, 0);
            c0 = __builtin_amdgcn_mfma_f32_16x16x32_bf16(pa[0][2], q2, c0, 0, 0, 0);
            c1 = __builtin_amdgcn_mfma_f32_16x16x32_bf16(pa[1][2], q2, c1, 0, 0, 0);
            c0 = __builtin_amdgcn_mfma_f32_16x16x32_bf16(pa[0][3], q3, c0, 0, 0, 0);
            c1 = __builtin_amdgcn_mfma_f32_16x16x32_bf16(pa[1][3], q3, c1, 0, 0, 0);
            int jg = (wv * 8 + f) * 16 + l15;
            float bias = b2f[cond * 1024 + jg];
            float t0 = c0[0] + bias, t1 = c0[1] + bias, t2 = c0[2] + bias, t3 = c0[3] + bias;
            float u0 = c1[0] + bias, u1 = c1[1] + bias, u2 = c1[2] + bias, u3 = c1[3] + bias;
            sq[0][0] += t0*t0; sq[0][1] += t1*t1; sq[0][2] += t2*t2; sq[0][3] += t3*t3;
            sq[1][0] += u0*u0; sq[1][1] += u1*u1; sq[1][2] += u2*u2; sq[1][3] += u3*u3;
            vals[f][0] = pack2(t0, t1); vals[f][1] = pack2(t2, t3);
            vals[f][2] = pack2(u0, u1); vals[f][3] = pack2(u2, u3);
        }
        // per-row sums: shfl over l15 -> LDS across waves
#pragma unroll
        for (int rg = 0; rg < 2; ++rg)
#pragma unroll
            for (int v = 0; v < 4; ++v) {
                float s = sq[rg][v];
                s += __shfl_xor(s, 1); s += __shfl_xor(s, 2);
                s += __shfl_xor(s, 4); s += __shfl_xor(s, 8);
                if (l15 == 0) sqs[(rg * 16 + kg * 4 + v) * 8 + wv] = s;
            }
        __syncthreads();
        float invn[2][4];
#pragma unroll
        for (int rg = 0; rg < 2; ++rg)
#pragma unroll
            for (int v = 0; v < 4; ++v) {
                int r = rg * 16 + kg * 4 + v;
                float s = sqs[r*8+0] + sqs[r*8+1] + sqs[r*8+2] + sqs[r*8+3]
                        + sqs[r*8+4] + sqs[r*8+5] + sqs[r*8+6] + sqs[r*8+7];
                invn[rg][v] = 1.0f / (sqrtf(s) + 1e-10f);
            }
        // ---- normalized store ----
#pragma unroll
        for (int f = 0; f < 8; ++f) {
            int jg = (wv * 8 + f) * 16 + l15;
#pragma unroll
            for (int rg = 0; rg < 2; ++rg) {
                unsigned p0 = vals[f][rg * 2], p1 = vals[f][rg * 2 + 1];
                float w0 = unpk(p0, 0), w1v = unpk(p0, 1), w2v = unpk(p1, 0), w3v = unpk(p1, 1);
                if (bbs[rg][0] >= 0) out[(size_t)bbs[rg][0] * D_ + jg] = w0  * invn[rg][0];
                if (bbs[rg][1] >= 0) out[(size_t)bbs[rg][1] * D_ + jg] = w1v * invn[rg][1];
                if (bbs[rg][2] >= 0) out[(size_t)bbs[rg][2] * D_ + jg] = w2v * invn[rg][2];
                if (bbs[rg][3] >= 0) out[(size_t)bbs[rg][3] * D_ + jg] = w3v * invn[rg][3];
            }
        }
        __syncthreads();   // protect LDS for next subtile
    }
}

__global__ void k_fin(const float* __restrict__ ep, float* __restrict__ out) {
    float s = 0.0f;
#pragma unroll
    for (int i = 0; i < 16; ++i) s += ep[i];
    out[BD] = 0.0f;
    out[BD + 1] = sqrtf(s);
}

extern "C" void kernel_launch(void* const* d_in, const int* in_sizes, int n_in,
                              void* d_out, int out_size, void* d_ws, size_t ws_size,
                              hipStream_t stream) {
    const float* x  = (const float*)d_in[0];
    const int*   c  = (const int*)d_in[1];
    const float* W1 = (const float*)d_in[2];
    const float* b1 = (const float*)d_in[3];
    const float* W2 = (const float*)d_in[4];
    const float* b2 = (const float*)d_in[5];
    float* out = (float*)d_out;
    char* ws = (char*)d_ws;
    int* wsi = (int*)ws;
    float* ep   = (float*)(ws + 131072);
    __bf16* w1s = (__bf16*)(ws + 262144);
    __bf16* w2s = (__bf16*)(ws + 4456448);
    __bf16* xbf = (__bf16*)(ws + 8650752);

    k_sort<<<1, 1024, 0, stream>>>(c, wsi, ep);
    k_prep<<<1280, 256, 0, stream>>>(x, W1, W2, out, xbf, w1s, w2s, wsi + 20480, ep);
    k_f<<<8 * SLOTS, 512, 0, stream>>>(xbf, w1s, w2s, b1, b2, wsi, out);
    k_fin<<<1, 1, 0, stream>>>(ep, out);
}

// Round 9
// 89.297 us; speedup vs baseline: 1.1805x; 1.0206x over previous
//
#include <hip/hip_runtime.h>
#include <hip/hip_bf16.h>
#include <math.h>

// B=8192, D=1024, H=128, C=16
// out tuple: masked[B*D], mask_norm(0.0), embed_norm(||x||F), x[B*D] -> f32
#define B_ 8192
#define D_ 1024
#define H_ 128
#define C_ 16
#define BD (B_*D_)
#define SUBR 32             // rows per subtile (padded per cond)
#define SLOTS 34            // slots per XCD; grid = 8*34 = 272
#define MAXSUB 300

using bf16x8 = __attribute__((ext_vector_type(8))) __bf16;
using f32x4  = __attribute__((ext_vector_type(4))) float;
typedef unsigned short ushort_t;

// ws layout (bytes):
//   int 16      : nsub[8]
//   int 32      : subtbl[8][300][3] (cond, prow0, end)
//   int 8192    : sidx[8704]  padded sorted-pos -> orig row   (byte 32768)
//   int 20480   : inv[8192]   orig row -> padded sorted-pos   (byte 81920)
//   131072      : ep[16] f32
//   262144      : w1s bf16 (4 MiB)  [cond][jf8][ks32][lane64][8]
//   4456448     : w2s bf16 (4 MiB)  [cond][jf64][ks4][lane64][8]
//   8650752     : xbf bf16 (~17 MiB) [subtile][rg2][ks32][lane64][8]

__device__ inline bf16x8 cvt8(float4 a, float4 b) {
    bf16x8 r;
    r[0] = (__bf16)a.x; r[1] = (__bf16)a.y; r[2] = (__bf16)a.z; r[3] = (__bf16)a.w;
    r[4] = (__bf16)b.x; r[5] = (__bf16)b.y; r[6] = (__bf16)b.z; r[7] = (__bf16)b.w;
    return r;
}
__device__ inline unsigned pack2(float a, float b) {
    unsigned ua = __builtin_bit_cast(unsigned short, (__bf16)a);
    unsigned ub = __builtin_bit_cast(unsigned short, (__bf16)b);
    return ua | (ub << 16);
}

// ---- histogram + padded per-XCD subtile table + scatter (fwd & inverse); zeroes ep ----
__global__ __launch_bounds__(1024) void k_sort(const int* __restrict__ c,
                                               int* __restrict__ w,
                                               float* __restrict__ ep) {
    __shared__ int hist[C_], base[C_];
    int tid = threadIdx.x;
    if (tid < C_) { hist[tid] = 0; ep[tid] = 0.0f; }
    __syncthreads();
    int myc[8];
#pragma unroll
    for (int i = 0; i < 8; ++i) {
        myc[i] = c[tid * 8 + i];
        atomicAdd(&hist[myc[i]], 1);
    }
    __syncthreads();
    if (tid == 0) {
        int off = 0; int ns[8] = {0,0,0,0,0,0,0,0};
        for (int cc = 0; cc < C_; ++cc) {
            int cnt = hist[cc]; base[cc] = off;
            int nt = (cnt + SUBR - 1) >> 5;
            int xcd = cc >> 1;
            for (int t = 0; t < nt; ++t) {
                int s = ns[xcd]++;
                int* e = &w[32 + (xcd * MAXSUB + s) * 3];
                e[0] = cc; e[1] = off + t * SUBR; e[2] = off + cnt;
            }
            off += nt * SUBR;              // padded to 32-row alignment
        }
        for (int xx = 0; xx < 8; ++xx) w[16 + xx] = ns[xx];
    }
    __syncthreads();
#pragma unroll
    for (int i = 0; i < 8; ++i) {
        int b = tid * 8 + i;
        int pos = atomicAdd(&base[myc[i]], 1);
        w[8192 + pos]  = b;     // sidx (padded positions)
        w[20480 + b]   = pos;   // inverse
    }
}

// ---- prep: x -> fragment-ordered bf16 + x copy + ||x||^2 ; W1,W2 -> bf16 streams ----
__global__ __launch_bounds__(256) void k_prep(const float* __restrict__ x,
                                              const float* __restrict__ W1f,
                                              const float* __restrict__ W2f,
                                              float* __restrict__ out,
                                              __bf16* __restrict__ xbf,
                                              __bf16* __restrict__ w1s,
                                              __bf16* __restrict__ w2s,
                                              const int* __restrict__ inv,
                                              float* __restrict__ ep) {
    int bid = blockIdx.x, tid = threadIdx.x;
    if (bid < 1024) {                       // x: 8 rows per block
        float xsq = 0.0f;
#pragma unroll
        for (int u = 0; u < 4; ++u) {
            int r = bid * 8 + u * 2 + (tid >> 7);
            int m = tid & 127;              // 16B chunk index within row
            const float* xs = x + (size_t)r * D_ + m * 8;
            float4 pv = *(const float4*)xs, qv = *(const float4*)(xs + 4);
            float2* xo = (float2*)(out + (size_t)BD + 2 + (size_t)r * D_ + m * 8);
            xo[0] = make_float2(pv.x, pv.y); xo[1] = make_float2(pv.z, pv.w);
            xo[2] = make_float2(qv.x, qv.y); xo[3] = make_float2(qv.z, qv.w);
            int pr = inv[r];
            int blk = pr >> 5, rg = (pr >> 4) & 1, r15 = pr & 15;
            int ks = m >> 2, kg = m & 3;
            size_t de = (size_t)blk * 32768 + (rg * 32 + ks) * 512 + (kg * 16 + r15) * 8;
            *(bf16x8*)(xbf + de) = cvt8(pv, qv);
            xsq += pv.x*pv.x + pv.y*pv.y + pv.z*pv.z + pv.w*pv.w
                 + qv.x*qv.x + qv.y*qv.y + qv.z*qv.z + qv.w*qv.w;
        }
        float s = xsq;
        s += __shfl_xor(s, 1);  s += __shfl_xor(s, 2);  s += __shfl_xor(s, 4);
        s += __shfl_xor(s, 8);  s += __shfl_xor(s, 16); s += __shfl_xor(s, 32);
        __shared__ float red[4];
        int lane = tid & 63, wv = tid >> 6;
        if (lane == 0) red[wv] = s;
        __syncthreads();
        if (tid == 0) atomicAdd(&ep[bid & 15], red[0] + red[1] + red[2] + red[3]);
    } else if (bid < 1152) {                // W1 -> w1s [cond][jf8][ks32][lane]
        int wb = bid - 1024;
#pragma unroll
        for (int u = 0; u < 8; ++u) {
            int g = wb * 2048 + u * 256 + tid;
            int cond = g >> 14, jf = (g >> 11) & 7, ks = (g >> 6) & 31, lam = g & 63;
            int l15 = lam & 15, kg = lam >> 4;
            const float* src = W1f + ((size_t)cond * 128 + jf * 16 + l15) * 1024 + ks * 32 + kg * 8;
            *(bf16x8*)(w1s + (size_t)g * 8) = cvt8(*(const float4*)src, *(const float4*)(src + 4));
        }
    } else {                                // W2 -> w2s [cond][jf64][ks4][lane]
        int wb = bid - 1152;
#pragma unroll
        for (int u = 0; u < 8; ++u) {
            int g = wb * 2048 + u * 256 + tid;
            int cond = g >> 14, jf = (g >> 8) & 63, ks = (g >> 6) & 3, lam = g & 63;
            int l15 = lam & 15, kg = lam >> 4;
            const float* src = W2f + ((size_t)cond * 1024 + jf * 16 + l15) * 128 + ks * 32 + kg * 8;
            *(bf16x8*)(w2s + (size_t)g * 8) = cvt8(*(const float4*)src, *(const float4*)(src + 4));
        }
    }
}

// ---- fused MLP + normalize: 512 thr, 32-row subtile, LDS out-tile, no spills ----
__global__ __launch_bounds__(512, 2) void k_f(const __bf16* __restrict__ xbf,
                                              const __bf16* __restrict__ w1s,
                                              const __bf16* __restrict__ w2s,
                                              const float* __restrict__ b1f,
                                              const float* __restrict__ b2f,
                                              const int* __restrict__ wsi,
                                              float* __restrict__ out) {
    int xcd = blockIdx.x & 7, slot0 = blockIdx.x >> 3;
    int nsub = wsi[16 + xcd];
    const int* sidx = wsi + 8192;

    __shared__ ulong2 lds_raw[4096];        // 64 KB: x frags -> Hs -> bf16 out-tile
    char* lds = (char*)lds_raw;
    ushort_t* Hs = (ushort_t*)lds;
    unsigned* Ot32 = (unsigned*)lds;        // [rowpair16][col1024] u32 = rows (2r,2r+1)
    __shared__ float sqs[32 * 8];

    int tid = threadIdx.x, wv = tid >> 6, lane = tid & 63, l15 = lane & 15, kg = lane >> 4;

    for (int si = slot0; si < nsub; si += SLOTS) {
        const int* e = wsi + 32 + (xcd * MAXSUB + si) * 3;
        int cond = e[0], prow0 = e[1], end = e[2];
        int blk = prow0 >> 5;

        // ---- stage x subtile: 64 KB contiguous copy ----
        {
            const char* src = (const char*)xbf + (size_t)blk * 65536 + tid * 16;
#pragma unroll
            for (int i = 0; i < 8; ++i) {
                bf16x8 v = *(const bf16x8*)(src + i * 8192);
                *(bf16x8*)(lds + i * 8192 + tid * 16) = v;
            }
        }
        __syncthreads();

        // ---- L1: wave wv computes h cols [wv*16,+16) for 32 rows ----
        const char* bA = (const char*)w1s + (size_t)cond * 262144 + wv * 32768 + lane * 16;
        f32x4 a00 = {}, a01 = {}, a10 = {}, a11 = {};
#pragma unroll 8
        for (int ks = 0; ks < 32; ++ks) {
            bf16x8 b  = *(const bf16x8*)(bA + ks * 1024);
            bf16x8 x0 = *(const bf16x8*)(lds + ks * 1024 + lane * 16);
            bf16x8 x1 = *(const bf16x8*)(lds + 32768 + ks * 1024 + lane * 16);
            if (ks & 1) {
                a01 = __builtin_amdgcn_mfma_f32_16x16x32_bf16(x0, b, a01, 0, 0, 0);
                a11 = __builtin_amdgcn_mfma_f32_16x16x32_bf16(x1, b, a11, 0, 0, 0);
            } else {
                a00 = __builtin_amdgcn_mfma_f32_16x16x32_bf16(x0, b, a00, 0, 0, 0);
                a10 = __builtin_amdgcn_mfma_f32_16x16x32_bf16(x1, b, a10, 0, 0, 0);
            }
        }
        __syncthreads();   // x reads done before Hs overwrites region

        // ---- h + b1 -> Hs (swizzled bf16) ----
        {
            int j0 = wv * 16 + l15;
            float bias = b1f[cond * 128 + j0];
            int sl0 = j0 >> 3, jb = j0 & 7;
#pragma unroll
            for (int v = 0; v < 4; ++v) {
                int r0 = kg * 4 + v;
                __bf16 h0 = (__bf16)(a00[v] + a01[v] + bias);
                __bf16 h1 = (__bf16)(a10[v] + a11[v] + bias);
                Hs[r0 * 128 + ((sl0 ^ (r0 & 7)) * 8) + jb] = __builtin_bit_cast(ushort_t, h0);
                int r1 = 16 + r0;
                Hs[r1 * 128 + ((sl0 ^ (r1 & 7)) * 8) + jb] = __builtin_bit_cast(ushort_t, h1);
            }
        }
        __syncthreads();

        // ---- pa fragments ----
        bf16x8 pa[2][4];
#pragma unroll
        for (int rg = 0; rg < 2; ++rg)
#pragma unroll
            for (int i = 0; i < 4; ++i)
                pa[rg][i] = *(const bf16x8*)(Hs + (rg * 16 + l15) * 128 + (((i * 4 + kg) ^ (l15 & 7)) * 8));
        __syncthreads();   // Hs consumed; Ot32 may now overwrite

        // ---- L2: wave wv owns out cols [wv*128,+128); results -> LDS out-tile ----
        const char* w2b = (const char*)w2s + (size_t)cond * 262144 + wv * 32768 + lane * 16;
        float sq[2][4] = {{0,0,0,0},{0,0,0,0}};
        unsigned cswz = (unsigned)((kg & 1) << 4);
#pragma unroll
        for (int f = 0; f < 8; ++f) {
            bf16x8 q0 = *(const bf16x8*)(w2b + f * 4096);
            bf16x8 q1 = *(const bf16x8*)(w2b + f * 4096 + 1024);
            bf16x8 q2 = *(const bf16x8*)(w2b + f * 4096 + 2048);
            bf16x8 q3 = *(const bf16x8*)(w2b + f * 4096 + 3072);
            f32x4 c0 = {}, c1 = {};
            c0 = __builtin_amdgcn_mfma_f32_16x16x32_bf16(pa[0][0], q0, c0, 0, 0, 0);
            c1 = __builtin_amdgcn_mfma_f32_16x16x32_bf16(pa[1][0], q0, c1, 0, 0, 0);
            c0 = __builtin_amdgcn_mfma_f32_16x16x32_bf16(pa[0][1], q1, c0, 0, 0, 0);
            c1 = __builtin_amdgcn_mfma_f32_16x16x32_bf16(pa[1][1], q1, c1, 0, 0, 0);
            c0 = __builtin_amdgcn_mfma_f32_16x16x32_bf16(pa[0][2], q2, c0, 0, 0, 0);
            c1 = __builtin_amdgcn_mfma_f32_16x16x32_bf16(pa[1][2], q2, c1, 0, 0, 0);
            c0 = __builtin_amdgcn_mfma_f32_16x16x32_bf16(pa[0][3], q3, c0, 0, 0, 0);
            c1 = __builtin_amdgcn_mfma_f32_16x16x32_bf16(pa[1][3], q3, c1, 0, 0, 0);
            int jg = (wv * 8 + f) * 16 + l15;
            float bias = b2f[cond * 1024 + jg];
            float t0 = c0[0] + bias, t1 = c0[1] + bias, t2 = c0[2] + bias, t3 = c0[3] + bias;
            float u0 = c1[0] + bias, u1 = c1[1] + bias, u2 = c1[2] + bias, u3 = c1[3] + bias;
            sq[0][0] += t0*t0; sq[0][1] += t1*t1; sq[0][2] += t2*t2; sq[0][3] += t3*t3;
            sq[1][0] += u0*u0; sq[1][1] += u1*u1; sq[1][2] += u2*u2; sq[1][3] += u3*u3;
            unsigned jc = (unsigned)jg ^ cswz;
            Ot32[(kg * 2    ) * 1024 + jc] = pack2(t0, t1);
            Ot32[(kg * 2 + 1) * 1024 + jc] = pack2(t2, t3);
            Ot32[(8 + kg * 2    ) * 1024 + jc] = pack2(u0, u1);
            Ot32[(8 + kg * 2 + 1) * 1024 + jc] = pack2(u2, u3);
        }
        // per-row sums: shfl over l15 -> LDS across waves
#pragma unroll
        for (int rg = 0; rg < 2; ++rg)
#pragma unroll
            for (int v = 0; v < 4; ++v) {
                float s = sq[rg][v];
                s += __shfl_xor(s, 1); s += __shfl_xor(s, 2);
                s += __shfl_xor(s, 4); s += __shfl_xor(s, 8);
                if (l15 == 0) sqs[(rg * 16 + kg * 4 + v) * 8 + wv] = s;
            }
        __syncthreads();

        // ---- fused normalize + fully-coalesced store: wave wv -> rows [wv*4,+4) ----
#pragma unroll
        for (int rr = 0; rr < 4; ++rr) {
            int r = wv * 4 + rr;
            int pr = prow0 + r;
            if (pr < end) {
                int orow = sidx[pr];
                float s = sqs[r*8+0] + sqs[r*8+1] + sqs[r*8+2] + sqs[r*8+3]
                        + sqs[r*8+4] + sqs[r*8+5] + sqs[r*8+6] + sqs[r*8+7];
                float inv = 1.0f / (sqrtf(s) + 1e-10f);
                int hi = (r & 1) * 16;
                unsigned rswz = (unsigned)(((r >> 2) & 1) << 4);
                const unsigned* base = Ot32 + (r >> 1) * 1024;
                float4* go = (float4*)(out + (size_t)orow * D_);
#pragma unroll
                for (int it = 0; it < 4; ++it) {
                    unsigned cu = (unsigned)((lane + it * 64) * 4) ^ rswz;
                    uint4 u = *(const uint4*)(base + cu);
                    float4 v;
                    v.x = (float)__builtin_bit_cast(__bf16, (ushort_t)(u.x >> hi)) * inv;
                    v.y = (float)__builtin_bit_cast(__bf16, (ushort_t)(u.y >> hi)) * inv;
                    v.z = (float)__builtin_bit_cast(__bf16, (ushort_t)(u.z >> hi)) * inv;
                    v.w = (float)__builtin_bit_cast(__bf16, (ushort_t)(u.w >> hi)) * inv;
                    go[lane + it * 64] = v;
                }
            }
        }
        __syncthreads();   // protect LDS for next subtile
    }
}

__global__ void k_fin(const float* __restrict__ ep, float* __restrict__ out) {
    float s = 0.0f;
#pragma unroll
    for (int i = 0; i < 16; ++i) s += ep[i];
    out[BD] = 0.0f;
    out[BD + 1] = sqrtf(s);
}

extern "C" void kernel_launch(void* const* d_in, const int* in_sizes, int n_in,
                              void* d_out, int out_size, void* d_ws, size_t ws_size,
                              hipStream_t stream) {
    const float* x  = (const float*)d_in[0];
    const int*   c  = (const int*)d_in[1];
    const float* W1 = (const float*)d_in[2];
    const float* b1 = (const float*)d_in[3];
    const float* W2 = (const float*)d_in[4];
    const float* b2 = (const float*)d_in[5];
    float* out = (float*)d_out;
    char* ws = (char*)d_ws;
    int* wsi = (int*)ws;
    float* ep   = (float*)(ws + 131072);
    __bf16* w1s = (__bf16*)(ws + 262144);
    __bf16* w2s = (__bf16*)(ws + 4456448);
    __bf16* xbf = (__bf16*)(ws + 8650752);

    k_sort<<<1, 1024, 0, stream>>>(c, wsi, ep);
    k_prep<<<1280, 256, 0, stream>>>(x, W1, W2, out, xbf, w1s, w2s, wsi + 20480, ep);
    k_f<<<8 * SLOTS, 512, 0, stream>>>(xbf, w1s, w2s, b1, b2, wsi, out);
    k_fin<<<1, 1, 0, stream>>>(ep, out);
}